// Round 5
// baseline (165.162 us; speedup 1.0000x reference)
//
#include <hip/hip_runtime.h>

typedef __attribute__((ext_vector_type(8))) short bf16x8;
typedef __attribute__((ext_vector_type(4))) float f32x4;

#define DD 64
#define SS 20
#define NPW 16            // nodes per wave = one MFMA M-tile
#define NW  8             // waves per block
#define NPB (NPW * NW)    // 128 nodes per block

// swizzle: word index (0..63, 4B units) within a 256B X row; chunk(16B) ^= row&15
#define SWZ(u, w) ((((((w) >> 2)) ^ ((u) & 15)) << 2) | ((w) & 3))

__device__ __forceinline__ unsigned cvt_pk_bf16(float lo, float hi) {
    unsigned r;
    asm("v_cvt_pk_bf16_f32 %0, %1, %2" : "=v"(r) : "v"(lo), "v"(hi));
    return r;
}

// Block = 512 threads = 8 waves, 128 nodes; one fused launch, both sides.
// LDS 48KB/block -> 3 blocks/CU -> 24 waves/CU (75% occupancy) vs 12 before:
// the R4 counters showed latency-bound (VALU 13%, Mfma 0.8%, occ 37.5%), so
// double the resident waves to double memory-level parallelism.
__global__ __launch_bounds__(512, 6) void sage_mfma(
    const int*   __restrict__ u_nodes, const int* __restrict__ i_nodes,
    const int*   __restrict__ u_nbrs,  const int* __restrict__ i_nbrs,
    const float* __restrict__ u_table, const float* __restrict__ i_table,
    const float* __restrict__ Wsu, const float* __restrict__ bsu,
    const float* __restrict__ Wnu, const float* __restrict__ bnu,
    const float* __restrict__ Wsi, const float* __restrict__ bsi,
    const float* __restrict__ Wni, const float* __restrict__ bni,
    float* __restrict__ out, int N, int nblk_side)
{
    __shared__ unsigned BP[16 * 64 * 4];      // 16 B-frags x 64 lanes x 16B = 16 KB
    __shared__ unsigned XW[NW][NPW][64];      // per-wave bf16 X tile, swizzled: 32 KB

    const int tid    = threadIdx.x;
    const int lane   = tid & 63;
    const int wid    = tid >> 6;
    const int lane15 = lane & 15;
    const int grp    = lane >> 4;

    const bool item_side = (int)blockIdx.x >= nblk_side;
    const int  blk = item_side ? (int)blockIdx.x - nblk_side : (int)blockIdx.x;

    const int*   nodes = item_side ? i_nodes : u_nodes;
    const int*   nbrs  = item_side ? i_nbrs  : u_nbrs;
    const float* table = item_side ? i_table : u_table;
    const float* Ws    = item_side ? Wsi : Wsu;
    const float* bsp   = item_side ? bsi : bsu;
    const float* Wn    = item_side ? Wni : Wnu;
    const float* bnp   = item_side ? bni : bnu;
    float* o = out + (item_side ? (size_t)N * DD : 0);

    // ---- Phase 0: W2^T -> bf16 B-fragments in LDS ----
    // frag(t,c): lane l holds B[k = t*32 + (l>>4)*8 + i][n = c*16 + (l&15)],
    // B[k][n] = W2[n][k] (Ws for k<64, Wn for k>=64).
    for (int fid = wid; fid < 16; fid += NW) {
        const int t = fid >> 2, c = fid & 3;
        const int n  = c * 16 + lane15;
        const int kb = t * 32 + (grp << 3);
        const float* src = (kb < 64) ? (Ws + n * 64 + kb) : (Wn + n * 64 + (kb - 64));
        const float4 v0 = *(const float4*)(src);
        const float4 v1 = *(const float4*)(src + 4);
        uint4 p;
        p.x = cvt_pk_bf16(v0.x, v0.y);
        p.y = cvt_pk_bf16(v0.z, v0.w);
        p.z = cvt_pk_bf16(v1.x, v1.y);
        p.w = cvt_pk_bf16(v1.z, v1.w);
        *(uint4*)&BP[(fid * 64 + lane) * 4] = p;
    }

    float bcol[4];
    #pragma unroll
    for (int c = 0; c < 4; ++c) {
        const int col = c * 16 + lane15;
        bcol[c] = bsp[col] + bnp[col];
    }
    __syncthreads();

    const int n0 = blk * NPB + wid * NPW;
    if (n0 >= N) return;   // whole-wave tail guard (no barriers below)

    // self indices for this wave's 16 nodes, staged in lanes 0..15
    const int nd = nodes[min(n0 + lane15, N - 1)];

    // ---- gather 16 nodes in 4 sub-batches of 4 ----
    #pragma unroll
    for (int sb = 0; sb < 4; ++sb) {
        const int u  = sb * 4 + grp;                 // node owned by this group
        const int nn = min(n0 + u, N - 1);

        // neighbor indices of node nn staged across this group's 16 lanes
        const int  nb0 = nbrs[(size_t)nn * SS + lane15];                       // s=0..15
        const long f1  = min((long)nn * SS + 16 + lane15, (long)N * SS - 1);
        const int  nb1 = nbrs[f1];                                             // s=16..19 (lane15<4)

        // self row (1 dwordx4: 4 rows, one per group)
        const int sidx = __shfl(nd, u, 64);
        const float4 self4 = ((const float4*)(table + (size_t)sidx * DD))[lane15];

        float4 agg = {0.f, 0.f, 0.f, 0.f};
        #pragma unroll
        for (int b = 0; b < SS; ++b) {
            const int idx = (b < 16) ? __shfl(nb0, (lane & 48) | b, 64)
                                     : __shfl(nb1, (lane & 48) | (b - 16), 64);
            const float4 r4 = ((const float4*)(table + (size_t)idx * DD))[lane15];
            agg.x += r4.x; agg.y += r4.y; agg.z += r4.z; agg.w += r4.w;
        }
        const float is = 1.0f / SS;

        // pack to bf16 and write swizzled XW row u (lane m holds dims 4m..4m+3)
        const int m = lane15;
        uint2 pself, pagg;
        pself.x = cvt_pk_bf16(self4.x, self4.y);
        pself.y = cvt_pk_bf16(self4.z, self4.w);
        pagg.x  = cvt_pk_bf16(agg.x * is, agg.y * is);
        pagg.y  = cvt_pk_bf16(agg.z * is, agg.w * is);
        *(uint2*)&XW[wid][u][SWZ(u, 2 * m)]      = pself;   // k = 4m..4m+3
        *(uint2*)&XW[wid][u][SWZ(u, 32 + 2 * m)] = pagg;    // k = 64+4m..
    }
    // XW written & read by the same wave -> lgkmcnt dependence, no barrier.

    // ---- MFMA: M=16, N=64, K=128 ----
    union AB { uint4 u4; bf16x8 v; };
    const f32x4 zero = {0.f, 0.f, 0.f, 0.f};
    f32x4 acc[4] = {zero, zero, zero, zero};
    #pragma unroll
    for (int t = 0; t < 4; ++t) {
        const int r     = lane15;
        const int chunk = t * 4 + grp;               // k = chunk*8
        AB a;
        a.u4 = *(const uint4*)&XW[wid][r][((chunk ^ r) << 2)];
        #pragma unroll
        for (int c = 0; c < 4; ++c) {
            AB b;
            b.u4 = *(const uint4*)&BP[((t * 4 + c) * 64 + lane) * 4];
            acc[c] = __builtin_amdgcn_mfma_f32_16x16x32_bf16(a.v, b.v, acc[c], 0, 0, 0);
        }
    }

    // ---- Epilogue: bias, relu, row-norm (16-lane-group reduce), store ----
    float rl[4][4];
    float ssq[4] = {0.f, 0.f, 0.f, 0.f};
    #pragma unroll
    for (int c = 0; c < 4; ++c) {
        #pragma unroll
        for (int j = 0; j < 4; ++j) {
            const float v = fmaxf(acc[c][j] + bcol[c], 0.f);
            rl[c][j] = v;
            ssq[j] = fmaf(v, v, ssq[j]);
        }
    }
    #pragma unroll
    for (int j = 0; j < 4; ++j) {
        #pragma unroll
        for (int m = 1; m < 16; m <<= 1)
            ssq[j] += __shfl_xor(ssq[j], m, 64);
    }
    float inv[4];
    #pragma unroll
    for (int j = 0; j < 4; ++j)
        inv[j] = 1.0f / fmaxf(sqrtf(ssq[j]), 1e-12f);

    #pragma unroll
    for (int j = 0; j < 4; ++j) {
        const int row = (grp << 2) + j;              // C/D: row=(l>>4)*4+reg
        const int ni  = n0 + row;
        if (ni < N) {
            #pragma unroll
            for (int c = 0; c < 4; ++c)
                o[(size_t)ni * DD + c * 16 + lane15] = rl[c][j] * inv[j];
        }
    }
}

extern "C" void kernel_launch(void* const* d_in, const int* in_sizes, int n_in,
                              void* d_out, int out_size, void* d_ws, size_t ws_size,
                              hipStream_t stream) {
    const int*   user_nodes = (const int*)  d_in[0];
    const int*   item_nodes = (const int*)  d_in[1];
    const int*   user_nbrs  = (const int*)  d_in[2];
    const int*   item_nbrs  = (const int*)  d_in[3];
    const float* user_table = (const float*)d_in[4];
    const float* item_table = (const float*)d_in[5];
    const float* Wsu = (const float*)d_in[6];
    const float* bsu = (const float*)d_in[7];
    const float* Wnu = (const float*)d_in[8];
    const float* bnu = (const float*)d_in[9];
    const float* Wsi = (const float*)d_in[10];
    const float* bsi = (const float*)d_in[11];
    const float* Wni = (const float*)d_in[12];
    const float* bni = (const float*)d_in[13];

    float* out = (float*)d_out;
    const int N = in_sizes[0];
    const int nblk_side = (N + NPB - 1) / NPB;

    sage_mfma<<<2 * nblk_side, 512, 0, stream>>>(
        user_nodes, item_nodes, user_nbrs, item_nbrs,
        user_table, item_table,
        Wsu, bsu, Wnu, bnu, Wsi, bsi, Wni, bni,
        out, N, nblk_side);
}

// Round 6
// 108.909 us; speedup vs baseline: 1.5165x; 1.5165x over previous
//
#include <hip/hip_runtime.h>

typedef __attribute__((ext_vector_type(8))) short bf16x8;
typedef __attribute__((ext_vector_type(4))) float f32x4;

#define DD 64
#define SS 20
#define NPW 16            // nodes per wave = one MFMA M-tile
#define NPB 64            // nodes per block (4 waves)

// swizzle: word index (0..63, 4B units) within a 256B X row; chunk(16B) ^= row&15
#define SWZ(u, w) ((((((w) >> 2)) ^ ((u) & 15)) << 2) | ((w) & 3))

__device__ __forceinline__ unsigned cvt_pk_bf16(float lo, float hi) {
    unsigned r;
    asm("v_cvt_pk_bf16_f32 %0, %1, %2" : "=v"(r) : "v"(lo), "v"(hi));
    return r;
}

// ---- streaming fp32 -> bf16 table conversion (8 floats / thread / iter) ----
__global__ __launch_bounds__(256) void to_bf16(const float* __restrict__ src,
                                               uint* __restrict__ dst, long n8)
{
    const long stride = (long)gridDim.x * blockDim.x;
    for (long i = (long)blockIdx.x * blockDim.x + threadIdx.x; i < n8; i += stride) {
        const float4 a = ((const float4*)src)[2 * i];
        const float4 b = ((const float4*)src)[2 * i + 1];
        uint4 p;
        p.x = cvt_pk_bf16(a.x, a.y);
        p.y = cvt_pk_bf16(a.z, a.w);
        p.z = cvt_pk_bf16(b.x, b.y);
        p.w = cvt_pk_bf16(b.z, b.w);
        ((uint4*)dst)[i] = p;
    }
}

// Block = 256 threads = 4 waves, 64 nodes; one fused launch, both sides.
// Gather reads 128B bf16 rows (half the lines/bytes of fp32): 16-lane group g
// owns node u0+g; lane m loads uint2 = dims 4m..4m+3 of one row; one
// global_load_dwordx2 covers 4 rows (512B/wave). Self rows pass straight
// into the XW MFMA A-tile as raw bf16 bits; neighbor rows unpack (2 bit-ops
// per float) and accumulate fp32.
__global__ __launch_bounds__(256, 4) void sage_bf16(
    const int*  __restrict__ u_nodes, const int* __restrict__ i_nodes,
    const int*  __restrict__ u_nbrs,  const int* __restrict__ i_nbrs,
    const uint* __restrict__ u_tb,    const uint* __restrict__ i_tb,
    const float* __restrict__ Wsu, const float* __restrict__ bsu,
    const float* __restrict__ Wnu, const float* __restrict__ bnu,
    const float* __restrict__ Wsi, const float* __restrict__ bsi,
    const float* __restrict__ Wni, const float* __restrict__ bni,
    float* __restrict__ out, int N, int nblk_side)
{
    __shared__ unsigned BP[16 * 64 * 4];   // 16 B-frags x 64 lanes x 16B = 16 KB
    __shared__ unsigned XW[4][NPW][64];    // per-wave bf16 X tile, swizzled: 16 KB

    const int tid    = threadIdx.x;
    const int lane   = tid & 63;
    const int wid    = tid >> 6;
    const int lane15 = lane & 15;
    const int grp    = lane >> 4;

    const bool item_side = (int)blockIdx.x >= nblk_side;
    const int  blk = item_side ? (int)blockIdx.x - nblk_side : (int)blockIdx.x;

    const int*  nodes = item_side ? i_nodes : u_nodes;
    const int*  nbrs  = item_side ? i_nbrs  : u_nbrs;
    const uint* tb    = item_side ? i_tb    : u_tb;     // bf16 rows, 32 uints each
    const float* Ws   = item_side ? Wsi : Wsu;
    const float* bsp  = item_side ? bsi : bsu;
    const float* Wn   = item_side ? Wni : Wnu;
    const float* bnp  = item_side ? bni : bnu;
    float* o = out + (item_side ? (size_t)N * DD : 0);

    // ---- Phase 0: W2^T -> bf16 B-fragments in LDS ----
    #pragma unroll
    for (int it = 0; it < 4; ++it) {
        const int fid = it * 4 + wid;          // 0..15, wave-uniform
        const int t = fid >> 2, c = fid & 3;
        const int n  = c * 16 + lane15;
        const int kb = t * 32 + (grp << 3);
        const float* src = (kb < 64) ? (Ws + n * 64 + kb) : (Wn + n * 64 + (kb - 64));
        const float4 v0 = *(const float4*)(src);
        const float4 v1 = *(const float4*)(src + 4);
        uint4 p;
        p.x = cvt_pk_bf16(v0.x, v0.y);
        p.y = cvt_pk_bf16(v0.z, v0.w);
        p.z = cvt_pk_bf16(v1.x, v1.y);
        p.w = cvt_pk_bf16(v1.z, v1.w);
        *(uint4*)&BP[(fid * 64 + lane) * 4] = p;
    }

    float bcol[4];
    #pragma unroll
    for (int c = 0; c < 4; ++c) {
        const int col = c * 16 + lane15;
        bcol[c] = bsp[col] + bnp[col];
    }
    __syncthreads();

    const int n0 = blk * NPB + wid * NPW;
    if (n0 >= N) return;   // whole-wave tail guard (no barriers below)

    // self indices for this wave's 16 nodes, staged in lanes 0..15
    const int nd = nodes[min(n0 + lane15, N - 1)];

    // ---- gather 16 nodes in 4 sub-batches of 4 ----
    #pragma unroll
    for (int sb = 0; sb < 4; ++sb) {
        const int u  = sb * 4 + grp;                 // node owned by this group
        const int nn = min(n0 + u, N - 1);

        // neighbor indices of node nn staged across this group's 16 lanes
        const int  nb0 = nbrs[(size_t)nn * SS + lane15];                 // s=0..15
        const long f1  = min((long)nn * SS + 16 + lane15, (long)N * SS - 1);
        const int  nb1 = nbrs[f1];                                       // s=16..19

        // self row: raw bf16 bits, dims 4m..4m+3 in lane m of the group
        const int sidx = __shfl(nd, u, 64);
        const uint2 sv = ((const uint2*)(tb + (size_t)sidx * 32))[lane15];

        float a0 = 0.f, a1 = 0.f, a2 = 0.f, a3 = 0.f;
        #pragma unroll
        for (int b = 0; b < SS; ++b) {
            const int idx = (b < 16) ? __shfl(nb0, (lane & 48) | b, 64)
                                     : __shfl(nb1, (lane & 48) | (b - 16), 64);
            const uint2 r = ((const uint2*)(tb + (size_t)idx * 32))[lane15];
            a0 += __uint_as_float(r.x << 16);
            a1 += __uint_as_float(r.x & 0xffff0000u);
            a2 += __uint_as_float(r.y << 16);
            a3 += __uint_as_float(r.y & 0xffff0000u);
        }
        const float is = 1.0f / SS;

        const int m = lane15;
        uint2 pagg;
        pagg.x = cvt_pk_bf16(a0 * is, a1 * is);
        pagg.y = cvt_pk_bf16(a2 * is, a3 * is);
        *(uint2*)&XW[wid][u][SWZ(u, 2 * m)]      = sv;      // k = 4m..4m+3
        *(uint2*)&XW[wid][u][SWZ(u, 32 + 2 * m)] = pagg;    // k = 64+4m..
    }
    // XW written & read by the same wave -> lgkmcnt dependence, no barrier.

    // ---- MFMA: M=16, N=64, K=128 ----
    union AB { uint4 u4; bf16x8 v; };
    const f32x4 zero = {0.f, 0.f, 0.f, 0.f};
    f32x4 acc[4] = {zero, zero, zero, zero};
    #pragma unroll
    for (int t = 0; t < 4; ++t) {
        const int r     = lane15;
        const int chunk = t * 4 + grp;               // k = chunk*8
        AB a;
        a.u4 = *(const uint4*)&XW[wid][r][((chunk ^ r) << 2)];
        #pragma unroll
        for (int c = 0; c < 4; ++c) {
            AB b;
            b.u4 = *(const uint4*)&BP[((t * 4 + c) * 64 + lane) * 4];
            acc[c] = __builtin_amdgcn_mfma_f32_16x16x32_bf16(a.v, b.v, acc[c], 0, 0, 0);
        }
    }

    // ---- Epilogue: bias, relu, row-norm (16-lane-group reduce), store ----
    float rl[4][4];
    float ssq[4] = {0.f, 0.f, 0.f, 0.f};
    #pragma unroll
    for (int c = 0; c < 4; ++c) {
        #pragma unroll
        for (int j = 0; j < 4; ++j) {
            const float v = fmaxf(acc[c][j] + bcol[c], 0.f);
            rl[c][j] = v;
            ssq[j] = fmaf(v, v, ssq[j]);
        }
    }
    #pragma unroll
    for (int j = 0; j < 4; ++j) {
        #pragma unroll
        for (int m = 1; m < 16; m <<= 1)
            ssq[j] += __shfl_xor(ssq[j], m, 64);
    }
    float inv[4];
    #pragma unroll
    for (int j = 0; j < 4; ++j)
        inv[j] = 1.0f / fmaxf(sqrtf(ssq[j]), 1e-12f);

    #pragma unroll
    for (int j = 0; j < 4; ++j) {
        const int row = (grp << 2) + j;              // C/D: row=(l>>4)*4+reg
        const int ni  = n0 + row;
        if (ni < N) {
            #pragma unroll
            for (int c = 0; c < 4; ++c)
                o[(size_t)ni * DD + c * 16 + lane15] = rl[c][j] * inv[j];
        }
    }
}

// ---- fallback (R4 fp32-gather path) if d_ws can't hold the bf16 tables ----
__global__ __launch_bounds__(256, 4) void sage_fp32(
    const int*   __restrict__ u_nodes, const int* __restrict__ i_nodes,
    const int*   __restrict__ u_nbrs,  const int* __restrict__ i_nbrs,
    const float* __restrict__ u_table, const float* __restrict__ i_table,
    const float* __restrict__ Wsu, const float* __restrict__ bsu,
    const float* __restrict__ Wnu, const float* __restrict__ bnu,
    const float* __restrict__ Wsi, const float* __restrict__ bsi,
    const float* __restrict__ Wni, const float* __restrict__ bni,
    float* __restrict__ out, int N, int nblk_side)
{
    __shared__ unsigned BP[16 * 64 * 4];
    __shared__ unsigned XW[4][NPW][64];

    const int tid    = threadIdx.x;
    const int lane   = tid & 63;
    const int wid    = tid >> 6;
    const int lane15 = lane & 15;
    const int grp    = lane >> 4;

    const bool item_side = (int)blockIdx.x >= nblk_side;
    const int  blk = item_side ? (int)blockIdx.x - nblk_side : (int)blockIdx.x;

    const int*   nodes = item_side ? i_nodes : u_nodes;
    const int*   nbrs  = item_side ? i_nbrs  : u_nbrs;
    const float* table = item_side ? i_table : u_table;
    const float* Ws    = item_side ? Wsi : Wsu;
    const float* bsp   = item_side ? bsi : bsu;
    const float* Wn    = item_side ? Wni : Wnu;
    const float* bnp   = item_side ? bni : bnu;
    float* o = out + (item_side ? (size_t)N * DD : 0);

    #pragma unroll
    for (int it = 0; it < 4; ++it) {
        const int fid = it * 4 + wid;
        const int t = fid >> 2, c = fid & 3;
        const int n  = c * 16 + lane15;
        const int kb = t * 32 + (grp << 3);
        const float* src = (kb < 64) ? (Ws + n * 64 + kb) : (Wn + n * 64 + (kb - 64));
        const float4 v0 = *(const float4*)(src);
        const float4 v1 = *(const float4*)(src + 4);
        uint4 p;
        p.x = cvt_pk_bf16(v0.x, v0.y);
        p.y = cvt_pk_bf16(v0.z, v0.w);
        p.z = cvt_pk_bf16(v1.x, v1.y);
        p.w = cvt_pk_bf16(v1.z, v1.w);
        *(uint4*)&BP[(fid * 64 + lane) * 4] = p;
    }

    float bcol[4];
    #pragma unroll
    for (int c = 0; c < 4; ++c) bcol[c] = bsp[c * 16 + lane15] + bnp[c * 16 + lane15];
    __syncthreads();

    const int n0 = blk * NPB + wid * NPW;
    if (n0 >= N) return;

    const int nd = nodes[min(n0 + lane15, N - 1)];

    #pragma unroll
    for (int sb = 0; sb < 4; ++sb) {
        const int u  = sb * 4 + grp;
        const int nn = min(n0 + u, N - 1);
        const int  nb0 = nbrs[(size_t)nn * SS + lane15];
        const long f1  = min((long)nn * SS + 16 + lane15, (long)N * SS - 1);
        const int  nb1 = nbrs[f1];
        const int sidx = __shfl(nd, u, 64);
        const float4 self4 = ((const float4*)(table + (size_t)sidx * DD))[lane15];
        float4 agg = {0.f, 0.f, 0.f, 0.f};
        #pragma unroll
        for (int b = 0; b < SS; ++b) {
            const int idx = (b < 16) ? __shfl(nb0, (lane & 48) | b, 64)
                                     : __shfl(nb1, (lane & 48) | (b - 16), 64);
            const float4 r4 = ((const float4*)(table + (size_t)idx * DD))[lane15];
            agg.x += r4.x; agg.y += r4.y; agg.z += r4.z; agg.w += r4.w;
        }
        const float is = 1.0f / SS;
        const int m = lane15;
        uint2 pself, pagg;
        pself.x = cvt_pk_bf16(self4.x, self4.y);
        pself.y = cvt_pk_bf16(self4.z, self4.w);
        pagg.x  = cvt_pk_bf16(agg.x * is, agg.y * is);
        pagg.y  = cvt_pk_bf16(agg.z * is, agg.w * is);
        *(uint2*)&XW[wid][u][SWZ(u, 2 * m)]      = pself;
        *(uint2*)&XW[wid][u][SWZ(u, 32 + 2 * m)] = pagg;
    }

    union AB { uint4 u4; bf16x8 v; };
    const f32x4 zero = {0.f, 0.f, 0.f, 0.f};
    f32x4 acc[4] = {zero, zero, zero, zero};
    #pragma unroll
    for (int t = 0; t < 4; ++t) {
        const int r     = lane15;
        const int chunk = t * 4 + grp;
        AB a;
        a.u4 = *(const uint4*)&XW[wid][r][((chunk ^ r) << 2)];
        #pragma unroll
        for (int c = 0; c < 4; ++c) {
            AB b;
            b.u4 = *(const uint4*)&BP[((t * 4 + c) * 64 + lane) * 4];
            acc[c] = __builtin_amdgcn_mfma_f32_16x16x32_bf16(a.v, b.v, acc[c], 0, 0, 0);
        }
    }

    float rl[4][4];
    float ssq[4] = {0.f, 0.f, 0.f, 0.f};
    #pragma unroll
    for (int c = 0; c < 4; ++c) {
        #pragma unroll
        for (int j = 0; j < 4; ++j) {
            const float v = fmaxf(acc[c][j] + bcol[c], 0.f);
            rl[c][j] = v;
            ssq[j] = fmaf(v, v, ssq[j]);
        }
    }
    #pragma unroll
    for (int j = 0; j < 4; ++j) {
        #pragma unroll
        for (int m = 1; m < 16; m <<= 1) ssq[j] += __shfl_xor(ssq[j], m, 64);
    }
    float inv[4];
    #pragma unroll
    for (int j = 0; j < 4; ++j) inv[j] = 1.0f / fmaxf(sqrtf(ssq[j]), 1e-12f);
    #pragma unroll
    for (int j = 0; j < 4; ++j) {
        const int row = (grp << 2) + j;
        const int ni  = n0 + row;
        if (ni < N) {
            #pragma unroll
            for (int c = 0; c < 4; ++c)
                o[(size_t)ni * DD + c * 16 + lane15] = rl[c][j] * inv[j];
        }
    }
}

extern "C" void kernel_launch(void* const* d_in, const int* in_sizes, int n_in,
                              void* d_out, int out_size, void* d_ws, size_t ws_size,
                              hipStream_t stream) {
    const int*   user_nodes = (const int*)  d_in[0];
    const int*   item_nodes = (const int*)  d_in[1];
    const int*   user_nbrs  = (const int*)  d_in[2];
    const int*   item_nbrs  = (const int*)  d_in[3];
    const float* user_table = (const float*)d_in[4];
    const float* item_table = (const float*)d_in[5];
    const float* Wsu = (const float*)d_in[6];
    const float* bsu = (const float*)d_in[7];
    const float* Wnu = (const float*)d_in[8];
    const float* bnu = (const float*)d_in[9];
    const float* Wsi = (const float*)d_in[10];
    const float* bsi = (const float*)d_in[11];
    const float* Wni = (const float*)d_in[12];
    const float* bni = (const float*)d_in[13];

    float* out = (float*)d_out;
    const int N = in_sizes[0];
    const int nblk_side = (N + NPB - 1) / NPB;

    const long nu = in_sizes[4];   // user_table elements
    const long ni = in_sizes[5];   // item_table elements
    const size_t need = (size_t)(nu + ni) * 2;   // bf16 bytes

    if (ws_size >= need) {
        uint* u_tb = (uint*)d_ws;
        uint* i_tb = u_tb + (nu >> 1);   // nu bf16 = nu/2 uints
        const long nu8 = nu >> 3, ni8 = ni >> 3;
        const int cb = 2048;
        to_bf16<<<cb, 256, 0, stream>>>(user_table, u_tb, nu8);
        to_bf16<<<cb, 256, 0, stream>>>(item_table, i_tb, ni8);
        sage_bf16<<<2 * nblk_side, 256, 0, stream>>>(
            user_nodes, item_nodes, user_nbrs, item_nbrs,
            (const uint*)u_tb, (const uint*)i_tb,
            Wsu, bsu, Wnu, bnu, Wsi, bsi, Wni, bni,
            out, N, nblk_side);
    } else {
        sage_fp32<<<2 * nblk_side, 256, 0, stream>>>(
            user_nodes, item_nodes, user_nbrs, item_nbrs,
            user_table, item_table,
            Wsu, bsu, Wnu, bnu, Wsi, bsi, Wni, bni,
            out, N, nblk_side);
    }
}